// Round 1
// baseline (116.729 us; speedup 1.0000x reference)
//
#include <hip/hip_runtime.h>
#include <math.h>

#define NCELLS (64 * 128 * 128)
#define EPSV 1e-10f

// ws accumulator layout (floats):
// [0] = m (obj count), [1] = S_noobj_bce0, [2] = S_nresp_bce0,
// [3] = S_xy, [4] = S_wh, [5] = S_obj
#define NACC 6

__device__ __forceinline__ float sigmoidf_(float x) {
    return 1.0f / (1.0f + expf(-x));
}

// logaddexp(0, x) = max(x,0) + log1p(exp(-|x|))
__device__ __forceinline__ float softplusf_(float x) {
    return fmaxf(x, 0.0f) + log1pf(expf(-fabsf(x)));
}

__device__ __forceinline__ float iou_(float cx, float cy, float cw, float ch,
                                      float tx, float ty, float tw, float th) {
    float plx = cx - 0.5f * cw, ply = cy - 0.5f * ch;
    float prx = cx + 0.5f * cw, pry = cy + 0.5f * ch;
    float tlx = tx - 0.5f * tw, tly = ty - 0.5f * th;
    float trx = tx + 0.5f * tw, try_ = ty + 0.5f * th;
    float wx = fmaxf(fminf(prx, trx) - fmaxf(plx, tlx), 0.0f);
    float wy = fmaxf(fminf(pry, try_) - fmaxf(ply, tly), 0.0f);
    float inter = wx * wy;
    float area_p = cw * ch;
    float area_t = tw * th;
    return inter / (area_p + area_t - inter + EPSV);
}

__global__ void init_ws_kernel(float* ws) {
    int i = threadIdx.x;
    if (i < NACC) ws[i] = 0.0f;
}

__global__ __launch_bounds__(256) void yolo_main_kernel(
        const float* __restrict__ input,
        const float* __restrict__ target,
        float* __restrict__ ws) {
    float m_cnt = 0.0f, s_noobj = 0.0f, s_nresp = 0.0f;
    float s_xy = 0.0f, s_wh = 0.0f, s_obj = 0.0f;

    const float2* __restrict__ in2 = (const float2*)input;
    int stride = gridDim.x * blockDim.x;
    for (int cell = blockIdx.x * blockDim.x + threadIdx.x; cell < NCELLS; cell += stride) {
        // input: 10 floats per cell = 5x float2 (8B aligned: cell*40 bytes)
        float2 a0 = in2[(size_t)cell * 5 + 0];
        float2 a1 = in2[(size_t)cell * 5 + 1];
        float2 a2 = in2[(size_t)cell * 5 + 2];
        float2 a3 = in2[(size_t)cell * 5 + 3];
        float2 a4 = in2[(size_t)cell * 5 + 4];

        const float* __restrict__ t = target + (size_t)cell * 5;
        float t0 = t[0];
        float tx = t[1], ty = t[2], tw = t[3], th = t[4];

        float logit0 = a0.x;
        float logit1 = a2.y;
        float bce0_0 = softplusf_(logit0);
        float bce0_1 = softplusf_(logit1);

        bool obj = (t0 > 0.0f);
        if (!obj) {
            s_noobj += bce0_0 + bce0_1;
        } else {
            m_cnt += 1.0f;
            float cx0 = sigmoidf_(a0.y), cy0 = sigmoidf_(a1.x);
            float cw0 = sigmoidf_(a1.y), ch0 = sigmoidf_(a2.x);
            float cx1 = sigmoidf_(a3.x), cy1 = sigmoidf_(a3.y);
            float cw1 = sigmoidf_(a4.x), ch1 = sigmoidf_(a4.y);

            float iou0 = iou_(cx0, cy0, cw0, ch0, tx, ty, tw, th);
            float iou1 = iou_(cx1, cy1, cw1, ch1, tx, ty, tw, th);
            // jnp.argmax picks first index on ties -> box 1 only if strictly greater
            bool r1 = (iou1 > iou0);

            float rcx = r1 ? cx1 : cx0, rcy = r1 ? cy1 : cy0;
            float rcw = r1 ? cw1 : cw0, rch = r1 ? ch1 : ch0;
            float dx = rcx - tx, dy = rcy - ty;
            float dw = rcw - tw, dh = rch - th;
            s_xy += dx * dx + dy * dy;
            s_wh += dw * dw + dh * dh;
            // bce1 = bce0 - logit for the responsible box
            s_obj += r1 ? (bce0_1 - logit1) : (bce0_0 - logit0);
            // non-responsible box contributes bce0
            s_nresp += r1 ? bce0_0 : bce0_1;
        }
    }

    // wave (64-lane) reduction
    float vals[NACC] = {m_cnt, s_noobj, s_nresp, s_xy, s_wh, s_obj};
    #pragma unroll
    for (int i = 0; i < NACC; ++i) {
        float v = vals[i];
        #pragma unroll
        for (int off = 32; off > 0; off >>= 1) v += __shfl_down(v, off, 64);
        vals[i] = v;
    }

    __shared__ float sm[4][NACC];  // 256 threads = 4 waves
    int wave = threadIdx.x >> 6;
    int lane = threadIdx.x & 63;
    if (lane == 0) {
        #pragma unroll
        for (int i = 0; i < NACC; ++i) sm[wave][i] = vals[i];
    }
    __syncthreads();
    if (threadIdx.x < NACC) {
        int i = threadIdx.x;
        float s = sm[0][i] + sm[1][i] + sm[2][i] + sm[3][i];
        atomicAdd(&ws[i], s);
    }
}

__global__ void finalize_kernel(const float* __restrict__ ws, float* __restrict__ out) {
    if (threadIdx.x != 0 || blockIdx.x != 0) return;
    float m = ws[0];
    float n_noobj = (float)NCELLS - m;
    float loss_noobj = ws[1] / (n_noobj * 2.0f) + ws[2] / m;  // B=2 -> (B-1)=1
    float loss_xy = ws[3] / (m * 2.0f);
    float loss_wh = ws[4] / (m * 2.0f);
    float loss_obj = ws[5] / m;
    float loss = loss_noobj + loss_xy + loss_wh + loss_obj;
    out[0] = loss;
    out[1] = loss_noobj;
    out[2] = loss_xy;
    out[3] = loss_wh;
    out[4] = loss_obj;
}

extern "C" void kernel_launch(void* const* d_in, const int* in_sizes, int n_in,
                              void* d_out, int out_size, void* d_ws, size_t ws_size,
                              hipStream_t stream) {
    const float* input = (const float*)d_in[0];
    const float* target = (const float*)d_in[1];
    float* out = (float*)d_out;
    float* ws = (float*)d_ws;

    hipLaunchKernelGGL(init_ws_kernel, dim3(1), dim3(64), 0, stream, ws);
    hipLaunchKernelGGL(yolo_main_kernel, dim3(2048), dim3(256), 0, stream,
                       input, target, ws);
    hipLaunchKernelGGL(finalize_kernel, dim3(1), dim3(64), 0, stream, ws, out);
}

// Round 2
// 99.049 us; speedup vs baseline: 1.1785x; 1.1785x over previous
//
#include <hip/hip_runtime.h>
#include <math.h>

#define NCELLS (64 * 128 * 128)      // 1,048,576
#define CELLS_PER_THREAD 4
#define MAIN_BLOCK 256
#define MAIN_GRID (NCELLS / CELLS_PER_THREAD / MAIN_BLOCK)  // 1024
#define NACC 6
#define WS_STRIDE 8                   // pad block-partial rows to 8 floats
#define EPSV 1e-10f

// fast sigmoid / softplus via hardware exp/log (abs err ~1e-7, threshold 5e-2)
__device__ __forceinline__ float sigmoidf_(float x) {
    return 1.0f / (1.0f + __expf(-x));
}
__device__ __forceinline__ float softplusf_(float x) {
    // logaddexp(0,x) = max(x,0) + log(1 + exp(-|x|))
    return fmaxf(x, 0.0f) + __logf(1.0f + __expf(-fabsf(x)));
}

__device__ __forceinline__ float iou_(float cx, float cy, float cw, float ch,
                                      float tx, float ty, float tw, float th) {
    float plx = cx - 0.5f * cw, ply = cy - 0.5f * ch;
    float prx = cx + 0.5f * cw, pry = cy + 0.5f * ch;
    float tlx = tx - 0.5f * tw, tly = ty - 0.5f * th;
    float trx = tx + 0.5f * tw, try_ = ty + 0.5f * th;
    float wx = fmaxf(fminf(prx, trx) - fmaxf(plx, tlx), 0.0f);
    float wy = fmaxf(fminf(pry, try_) - fmaxf(ply, tly), 0.0f);
    float inter = wx * wy;
    return inter / (cw * ch + tw * th - inter + EPSV);
}

__global__ __launch_bounds__(MAIN_BLOCK) void yolo_main_kernel(
        const float4* __restrict__ in4,
        const float4* __restrict__ tg4,
        float* __restrict__ ws) {
    int tid = blockIdx.x * MAIN_BLOCK + threadIdx.x;

    // 4 cells/thread: 10 float4 of input (160B) + 5 float4 of target (80B),
    // all 16B-aligned. Issue all loads up front for memory-level parallelism.
    float r[40];
    float t[20];
    const float4* __restrict__ ip = in4 + (size_t)tid * 10;
    #pragma unroll
    for (int i = 0; i < 10; ++i) {
        float4 v = ip[i];
        r[i * 4 + 0] = v.x; r[i * 4 + 1] = v.y; r[i * 4 + 2] = v.z; r[i * 4 + 3] = v.w;
    }
    const float4* __restrict__ tp = tg4 + (size_t)tid * 5;
    #pragma unroll
    for (int i = 0; i < 5; ++i) {
        float4 v = tp[i];
        t[i * 4 + 0] = v.x; t[i * 4 + 1] = v.y; t[i * 4 + 2] = v.z; t[i * 4 + 3] = v.w;
    }

    float m_cnt = 0.0f, s_noobj = 0.0f, s_nresp = 0.0f;
    float s_xy = 0.0f, s_wh = 0.0f, s_obj = 0.0f;

    #pragma unroll
    for (int j = 0; j < CELLS_PER_THREAD; ++j) {
        const float* f = r + j * 10;   // [logit0, x0,y0,w0,h0, logit1, x1,y1,w1,h1]
        const float* tt = t + j * 5;   // [conf, tx,ty,tw,th]

        float logit0 = f[0], logit1 = f[5];
        float bce0_0 = softplusf_(logit0);
        float bce0_1 = softplusf_(logit1);

        float tx = tt[1], ty = tt[2], tw = tt[3], th = tt[4];
        bool obj = (tt[0] > 0.0f);

        if (!obj) {
            s_noobj += bce0_0 + bce0_1;
        } else {
            m_cnt += 1.0f;
            float cx0 = sigmoidf_(f[1]), cy0 = sigmoidf_(f[2]);
            float cw0 = sigmoidf_(f[3]), ch0 = sigmoidf_(f[4]);
            float cx1 = sigmoidf_(f[6]), cy1 = sigmoidf_(f[7]);
            float cw1 = sigmoidf_(f[8]), ch1 = sigmoidf_(f[9]);

            float iou0 = iou_(cx0, cy0, cw0, ch0, tx, ty, tw, th);
            float iou1 = iou_(cx1, cy1, cw1, ch1, tx, ty, tw, th);
            bool r1 = (iou1 > iou0);   // argmax first-index tie-break

            float rcx = r1 ? cx1 : cx0, rcy = r1 ? cy1 : cy0;
            float rcw = r1 ? cw1 : cw0, rch = r1 ? ch1 : ch0;
            float dx = rcx - tx, dy = rcy - ty;
            float dw = rcw - tw, dh = rch - th;
            s_xy += dx * dx + dy * dy;
            s_wh += dw * dw + dh * dh;
            s_obj += r1 ? (bce0_1 - logit1) : (bce0_0 - logit0);
            s_nresp += r1 ? bce0_0 : bce0_1;
        }
    }

    // 64-lane butterfly reduce, then cross-wave via LDS
    float vals[NACC] = {m_cnt, s_noobj, s_nresp, s_xy, s_wh, s_obj};
    #pragma unroll
    for (int i = 0; i < NACC; ++i) {
        float v = vals[i];
        #pragma unroll
        for (int off = 32; off > 0; off >>= 1) v += __shfl_down(v, off, 64);
        vals[i] = v;
    }

    __shared__ float sm[4][NACC];
    int wave = threadIdx.x >> 6;
    int lane = threadIdx.x & 63;
    if (lane == 0) {
        #pragma unroll
        for (int i = 0; i < NACC; ++i) sm[wave][i] = vals[i];
    }
    __syncthreads();
    if (threadIdx.x < NACC) {
        int i = threadIdx.x;
        ws[blockIdx.x * WS_STRIDE + i] = sm[0][i] + sm[1][i] + sm[2][i] + sm[3][i];
    }
}

__global__ __launch_bounds__(256) void yolo_finalize_kernel(
        const float* __restrict__ ws, float* __restrict__ out) {
    float acc[NACC] = {0, 0, 0, 0, 0, 0};
    for (int b = threadIdx.x; b < MAIN_GRID; b += 256) {
        #pragma unroll
        for (int i = 0; i < NACC; ++i) acc[i] += ws[b * WS_STRIDE + i];
    }
    #pragma unroll
    for (int i = 0; i < NACC; ++i) {
        float v = acc[i];
        #pragma unroll
        for (int off = 32; off > 0; off >>= 1) v += __shfl_down(v, off, 64);
        acc[i] = v;
    }
    __shared__ float sm[4][NACC];
    int wave = threadIdx.x >> 6;
    int lane = threadIdx.x & 63;
    if (lane == 0) {
        #pragma unroll
        for (int i = 0; i < NACC; ++i) sm[wave][i] = acc[i];
    }
    __syncthreads();
    if (threadIdx.x == 0) {
        float m       = sm[0][0] + sm[1][0] + sm[2][0] + sm[3][0];
        float s_noobj = sm[0][1] + sm[1][1] + sm[2][1] + sm[3][1];
        float s_nresp = sm[0][2] + sm[1][2] + sm[2][2] + sm[3][2];
        float s_xy    = sm[0][3] + sm[1][3] + sm[2][3] + sm[3][3];
        float s_wh    = sm[0][4] + sm[1][4] + sm[2][4] + sm[3][4];
        float s_obj   = sm[0][5] + sm[1][5] + sm[2][5] + sm[3][5];

        float n_noobj = (float)NCELLS - m;
        float loss_noobj = s_noobj / (n_noobj * 2.0f) + s_nresp / m;  // B=2
        float loss_xy = s_xy / (m * 2.0f);
        float loss_wh = s_wh / (m * 2.0f);
        float loss_obj = s_obj / m;
        out[0] = loss_noobj + loss_xy + loss_wh + loss_obj;
        out[1] = loss_noobj;
        out[2] = loss_xy;
        out[3] = loss_wh;
        out[4] = loss_obj;
    }
}

extern "C" void kernel_launch(void* const* d_in, const int* in_sizes, int n_in,
                              void* d_out, int out_size, void* d_ws, size_t ws_size,
                              hipStream_t stream) {
    const float4* in4 = (const float4*)d_in[0];
    const float4* tg4 = (const float4*)d_in[1];
    float* out = (float*)d_out;
    float* ws = (float*)d_ws;

    hipLaunchKernelGGL(yolo_main_kernel, dim3(MAIN_GRID), dim3(MAIN_BLOCK), 0, stream,
                       in4, tg4, ws);
    hipLaunchKernelGGL(yolo_finalize_kernel, dim3(1), dim3(256), 0, stream, ws, out);
}